// Round 12
// baseline (219.794 us; speedup 1.0000x reference)
//
#include <hip/hip_runtime.h>
#include <math.h>

#define L_SEQ 1024
#define M_ROWS 2048
#define PI_F 3.14159265358979323846f

typedef short bf16x8 __attribute__((ext_vector_type(8)));
typedef float f32x4 __attribute__((ext_vector_type(4)));

__device__ __forceinline__ unsigned short bf16_rne(float x) {
    union { float f; unsigned u; } v; v.f = x;
    unsigned r = v.u + 0x7fffu + ((v.u >> 16) & 1u);
    return (unsigned short)(r >> 16);
}
__device__ __forceinline__ float bf16_tof(unsigned short h) {
    union { unsigned u; float f; } v; v.u = ((unsigned)h) << 16;
    return v.f;
}
__device__ __forceinline__ void split2(float x, unsigned short &h, unsigned short &l) {
    h = bf16_rne(x);
    l = bf16_rne(x - bf16_tof(h));
}
__device__ __forceinline__ float gelu_exact(float x) {
    return 0.5f * x * (1.0f + erff(x * 0.70710678118654752f));
}
__device__ __forceinline__ f32x4 mfma16(bf16x8 a, bf16x8 b, f32x4 c) {
    return __builtin_amdgcn_mfma_f32_16x16x32_bf16(a, b, c, 0, 0, 0);
}
__device__ __forceinline__ void gload_lds16(const unsigned short* g, unsigned short* l) {
    __builtin_amdgcn_global_load_lds(
        (const __attribute__((address_space(1))) void*)g,
        (__attribute__((address_space(3))) void*)l, 16, 0, 0);
}

// Stage R x 32 bf16 tile into LDS (row = 64B), pre-swizzled source.
__device__ __forceinline__ void stage_tile(
    const unsigned short* __restrict__ src, int ld, int rowBase, int k0,
    unsigned short* lds_tile, int R)
{
    const int tid = threadIdx.x;
    if (tid < R * 4) {
        const int r = tid >> 2;
        const int c = (tid & 3) ^ ((r >> 1) & 3);
        const unsigned short* g = src + (size_t)(rowBase + r) * ld + k0 + c * 8;
        unsigned short* l = lds_tile + (tid >> 6) * 512;   // wave-uniform base
        gload_lds16(g, l);
    }
}

// Stage 128 rows x 32 k from f32 source: load, split hi/lo, ds_write_b128
// into the same swizzled layout stage_tile produces. 512 threads exactly.
__device__ __forceinline__ void stage_xf32(
    const float* __restrict__ src, int ld, int rowBase, int k0,
    unsigned short* dh, unsigned short* dl)
{
    const int tid = threadIdx.x;
    const int r = tid >> 2, slot = tid & 3;
    const float* p = src + (size_t)(rowBase + r) * ld + k0 + slot * 8;
    float4 a = *reinterpret_cast<const float4*>(p);
    float4 b = *reinterpret_cast<const float4*>(p + 4);
    bf16x8 h, l;
    unsigned short th, tl;
    split2(a.x, th, tl); h[0] = (short)th; l[0] = (short)tl;
    split2(a.y, th, tl); h[1] = (short)th; l[1] = (short)tl;
    split2(a.z, th, tl); h[2] = (short)th; l[2] = (short)tl;
    split2(a.w, th, tl); h[3] = (short)th; l[3] = (short)tl;
    split2(b.x, th, tl); h[4] = (short)th; l[4] = (short)tl;
    split2(b.y, th, tl); h[5] = (short)th; l[5] = (short)tl;
    split2(b.z, th, tl); h[6] = (short)th; l[6] = (short)tl;
    split2(b.w, th, tl); h[7] = (short)th; l[7] = (short)tl;
    const int addr = r * 32 + ((slot ^ ((r >> 1) & 3)) << 3);
    *reinterpret_cast<bf16x8*>(dh + addr) = h;
    *reinterpret_cast<bf16x8*>(dl + addr) = l;
}

// Stage 128 rows x 32 k of Y = LN-transformed sum of Rp chunks. Per-thread
// row stats (scale, mu, ri, nc) passed in registers.
__device__ __forceinline__ void stage_y(
    const float* __restrict__ Rp, int rowg, int nc, int k0,
    float scale, float mu, float ri,
    const float* __restrict__ lng, const float* __restrict__ lnb,
    unsigned short* dh, unsigned short* dl)
{
    const int tid = threadIdx.x;
    const int r = tid >> 2, slot = tid & 3;
    const int kk = k0 + slot * 8;
    const float* p = Rp + (size_t)rowg * 512 + kk;
    float4 a = *reinterpret_cast<const float4*>(p);
    float4 b = *reinterpret_cast<const float4*>(p + 4);
    for (int c = 1; c < nc; ++c) {
        const float* pc = p + (size_t)c * (M_ROWS * 512);
        float4 ac = *reinterpret_cast<const float4*>(pc);
        float4 bc = *reinterpret_cast<const float4*>(pc + 4);
        a.x += ac.x; a.y += ac.y; a.z += ac.z; a.w += ac.w;
        b.x += bc.x; b.y += bc.y; b.z += bc.z; b.w += bc.w;
    }
    float4 g0 = *reinterpret_cast<const float4*>(lng + kk);
    float4 g1 = *reinterpret_cast<const float4*>(lng + kk + 4);
    float4 c0 = *reinterpret_cast<const float4*>(lnb + kk);
    float4 c1 = *reinterpret_cast<const float4*>(lnb + kk + 4);
    float y[8];
    y[0] = (a.x*scale - mu)*ri*g0.x + c0.x;
    y[1] = (a.y*scale - mu)*ri*g0.y + c0.y;
    y[2] = (a.z*scale - mu)*ri*g0.z + c0.z;
    y[3] = (a.w*scale - mu)*ri*g0.w + c0.w;
    y[4] = (b.x*scale - mu)*ri*g1.x + c1.x;
    y[5] = (b.y*scale - mu)*ri*g1.y + c1.y;
    y[6] = (b.z*scale - mu)*ri*g1.z + c1.z;
    y[7] = (b.w*scale - mu)*ri*g1.w + c1.w;
    bf16x8 h, l;
    unsigned short th, tl;
#pragma unroll
    for (int e = 0; e < 8; ++e) { split2(y[e], th, tl); h[e] = (short)th; l[e] = (short)tl; }
    const int addr = r * 32 + ((slot ^ ((r >> 1) & 3)) << 3);
    *reinterpret_cast<bf16x8*>(dh + addr) = h;
    *reinterpret_cast<bf16x8*>(dl + addr) = l;
}

// LDS-staged split-bf16 GEMM core (both operands pre-split bf16 in global).
// 512 threads = 8 waves (2m x 4n). Block tile = (32*MI) x (64*NI).
template<int MI, int NI>
__device__ __forceinline__ void lds_gemm(
    unsigned short* lds,
    const unsigned short* Ah_, const unsigned short* Al_, int lda, int aRow,
    const unsigned short* Bh_, const unsigned short* Bl_, int ldb, int bRow,
    int k0, int nk, f32x4 (&acc)[MI][NI])
{
    constexpr int RA = MI * 32, RB = NI * 64;
    constexpr int SZA = RA * 32;
    constexpr int SZB = RB * 32;
    constexpr int BUF = 2 * SZA + 2 * SZB;
    const int tid = threadIdx.x, lane = tid & 63;
    const int wm = (tid >> 8) & 1;
    const int wn = (tid >> 6) & 3;

    stage_tile(Ah_, lda, aRow, k0, lds,                 RA);
    stage_tile(Al_, lda, aRow, k0, lds + SZA,           RA);
    stage_tile(Bh_, ldb, bRow, k0, lds + 2 * SZA,       RB);
    stage_tile(Bl_, ldb, bRow, k0, lds + 2 * SZA + SZB, RB);

    for (int ks = 0; ks < nk; ++ks) {
        const int cur = (ks & 1) * BUF;
        const int nxt = ((ks & 1) ^ 1) * BUF;
        __syncthreads();
        if (ks + 1 < nk) {
            const int kk = k0 + (ks + 1) * 32;
            stage_tile(Ah_, lda, aRow, kk, lds + nxt,                 RA);
            stage_tile(Al_, lda, aRow, kk, lds + nxt + SZA,           RA);
            stage_tile(Bh_, ldb, bRow, kk, lds + nxt + 2 * SZA,       RB);
            stage_tile(Bl_, ldb, bRow, kk, lds + nxt + 2 * SZA + SZB, RB);
        }
        const int lr = lane & 15, j = lane >> 4;
        bf16x8 ah[MI], al[MI], bh[NI], bl[NI];
#pragma unroll
        for (int mi = 0; mi < MI; ++mi) {
            const int r = wm * (MI * 16) + mi * 16 + lr;
            const int off = cur + r * 32 + ((j ^ ((r >> 1) & 3)) << 3);
            ah[mi] = *(const bf16x8*)(lds + off);
            al[mi] = *(const bf16x8*)(lds + off + SZA);
        }
#pragma unroll
        for (int ni = 0; ni < NI; ++ni) {
            const int r = wn * (NI * 16) + ni * 16 + lr;
            const int off = cur + 2 * SZA + r * 32 + ((j ^ ((r >> 1) & 3)) << 3);
            bh[ni] = *(const bf16x8*)(lds + off);
            bl[ni] = *(const bf16x8*)(lds + off + SZB);
        }
#pragma unroll
        for (int mi = 0; mi < MI; ++mi)
#pragma unroll
            for (int ni = 0; ni < NI; ++ni) {
                acc[mi][ni] = mfma16(ah[mi], bh[ni], acc[mi][ni]);
                acc[mi][ni] = mfma16(ah[mi], bl[ni], acc[mi][ni]);
                acc[mi][ni] = mfma16(al[mi], bh[ni], acc[mi][ni]);
            }
    }
}

// ---------------------------------------------------------------------------
// prep: weights only — transpose + hi/lo split into Wt[row=n][k].
// rows: [0,512)=Wk1^T, [512,1024)=Wq1^T, [1024,1536)=Wv^T,
//       [1536,2048)=Wo^T, [2048,2112)=Wk2^T, [2112,2176)=Wq2^T
// ---------------------------------------------------------------------------
__global__ __launch_bounds__(512) void prep(
    const float* __restrict__ Wk1, const float* __restrict__ Wq1,
    const float* __restrict__ Wv,  const float* __restrict__ Wo,
    const float* __restrict__ Wk2, const float* __restrict__ Wq2,
    unsigned short* __restrict__ Wt_h, unsigned short* __restrict__ Wt_l)
{
    const int u = blockIdx.x;
    const int tid = threadIdx.x;
    __shared__ float T[64 * 65];
    const int kT = u & 7, ty = u >> 3;
    const float* src; int srcN, dstRowBase, nBase;
    if (ty < 8)       { src = Wk1; srcN = 512; dstRowBase = 0;    nBase = ty * 64; }
    else if (ty < 16) { src = Wq1; srcN = 512; dstRowBase = 512;  nBase = (ty-8)*64; }
    else if (ty < 24) { src = Wv;  srcN = 512; dstRowBase = 1024; nBase = (ty-16)*64; }
    else if (ty < 32) { src = Wo;  srcN = 512; dstRowBase = 1536; nBase = (ty-24)*64; }
    else if (ty == 32){ src = Wk2; srcN = 64;  dstRowBase = 2048; nBase = 0; }
    else              { src = Wq2; srcN = 64;  dstRowBase = 2112; nBase = 0; }
    const int k0 = kT * 64;
    {
        const int r = tid >> 3, c0 = (tid & 7) * 8;
#pragma unroll
        for (int i = 0; i < 2; ++i) {
            float4 v = *reinterpret_cast<const float4*>(
                src + (size_t)(k0 + r) * srcN + nBase + c0 + i*4);
            T[r*65 + c0+i*4+0] = v.x; T[r*65 + c0+i*4+1] = v.y;
            T[r*65 + c0+i*4+2] = v.z; T[r*65 + c0+i*4+3] = v.w;
        }
    }
    __syncthreads();
    {
        const int n = tid >> 3, kk0 = (tid & 7) * 8;
        const size_t base = (size_t)(dstRowBase + nBase + n) * 512 + k0 + kk0;
#pragma unroll
        for (int i = 0; i < 8; ++i) {
            unsigned short h, l;
            split2(T[(kk0 + i)*65 + n], h, l);
            Wt_h[base + i] = h; Wt_l[base + i] = l;
        }
    }
}

// ---------------------------------------------------------------------------
// qkv: 192 units of 128x128. A staged from f32 x (split on the fly);
// B = Wt via global_load_lds. gelu on k/q segs, V transposed per batch.
// ---------------------------------------------------------------------------
__global__ __launch_bounds__(512) void qkv_mfma(
    const float* __restrict__ x,
    const unsigned short* __restrict__ Wt_h, const unsigned short* __restrict__ Wt_l,
    const float* __restrict__ bk1, const float* __restrict__ bq1, const float* __restrict__ bv,
    unsigned short* __restrict__ Hk_h, unsigned short* __restrict__ Hk_l,
    unsigned short* __restrict__ Hq_h, unsigned short* __restrict__ Hq_l,
    unsigned short* __restrict__ Vt_h, unsigned short* __restrict__ Vt_l)
{
    __shared__ __align__(16) unsigned short lds[32768];   // 64KB
    constexpr int SZA = 4096, SZB = 4096, BUF = 16384;
    const int tid = threadIdx.x, lane = tid & 63;
    const int nT = blockIdx.x % 12, mT = blockIdx.x / 12;
    const int mBase = mT * 128, nBase = nT * 128;
    const int wm = (tid >> 8) & 1, wn = (tid >> 6) & 3;
    f32x4 acc[4][2];
#pragma unroll
    for (int i = 0; i < 4; ++i)
#pragma unroll
        for (int jj = 0; jj < 2; ++jj) acc[i][jj] = (f32x4){0.f,0.f,0.f,0.f};

    stage_xf32(x, 512, mBase, 0, lds, lds + SZA);
    stage_tile(Wt_h, 512, nBase, 0, lds + 2*SZA, 128);
    stage_tile(Wt_l, 512, nBase, 0, lds + 2*SZA + SZB, 128);
    for (int ks = 0; ks < 16; ++ks) {
        const int cur = (ks & 1) * BUF;
        const int nxt = cur ^ BUF;
        __syncthreads();
        if (ks + 1 < 16) {
            const int kk = (ks + 1) * 32;
            stage_xf32(x, 512, mBase, kk, lds + nxt, lds + nxt + SZA);
            stage_tile(Wt_h, 512, nBase, kk, lds + nxt + 2*SZA, 128);
            stage_tile(Wt_l, 512, nBase, kk, lds + nxt + 2*SZA + SZB, 128);
        }
        const int lr = lane & 15, j = lane >> 4;
        bf16x8 ah[4], al[4], bh[2], bl[2];
#pragma unroll
        for (int mi = 0; mi < 4; ++mi) {
            const int r = wm*64 + mi*16 + lr;
            const int off = cur + r*32 + ((j ^ ((r>>1)&3)) << 3);
            ah[mi] = *(const bf16x8*)(lds + off);
            al[mi] = *(const bf16x8*)(lds + off + SZA);
        }
#pragma unroll
        for (int ni = 0; ni < 2; ++ni) {
            const int r = wn*32 + ni*16 + lr;
            const int off = cur + 2*SZA + r*32 + ((j ^ ((r>>1)&3)) << 3);
            bh[ni] = *(const bf16x8*)(lds + off);
            bl[ni] = *(const bf16x8*)(lds + off + SZB);
        }
#pragma unroll
        for (int mi = 0; mi < 4; ++mi)
#pragma unroll
            for (int ni = 0; ni < 2; ++ni) {
                acc[mi][ni] = mfma16(ah[mi], bh[ni], acc[mi][ni]);
                acc[mi][ni] = mfma16(ah[mi], bl[ni], acc[mi][ni]);
                acc[mi][ni] = mfma16(al[mi], bh[ni], acc[mi][ni]);
            }
    }
    const int seg = nBase >> 9;
    const float* bias = (seg == 0) ? bk1 : (seg == 1) ? bq1 : bv;
#pragma unroll
    for (int mi = 0; mi < 4; ++mi)
#pragma unroll
    for (int ni = 0; ni < 2; ++ni)
#pragma unroll
    for (int r = 0; r < 4; ++r) {
        const int row = mBase + wm*64 + mi*16 + (lane>>4)*4 + r;
        const int col = nBase + wn*32 + ni*16 + (lane&15);
        const int nW = col & 511;
        float v = acc[mi][ni][r] + bias[nW];
        if (seg < 2) v = gelu_exact(v);
        unsigned short h, l;
        split2(v, h, l);
        if (seg == 0)      { Hk_h[(size_t)row*512 + nW] = h; Hk_l[(size_t)row*512 + nW] = l; }
        else if (seg == 1) { Hq_h[(size_t)row*512 + nW] = h; Hq_l[(size_t)row*512 + nW] = l; }
        else {
            const size_t o = (size_t)((row >> 10)*512 + nW) * 1024 + (row & 1023);
            Vt_h[o] = h; Vt_l[o] = l;
        }
    }
}

// ---------------------------------------------------------------------------
// phase heads: 64 units of 64 rows; p = tanh(H@W2+b2)*pi -> [cos|sin] hi/lo.
// ---------------------------------------------------------------------------
__global__ __launch_bounds__(512) void phase_mfma(
    const unsigned short* __restrict__ Hk_h, const unsigned short* __restrict__ Hk_l,
    const unsigned short* __restrict__ Hq_h, const unsigned short* __restrict__ Hq_l,
    const unsigned short* __restrict__ Wt_h, const unsigned short* __restrict__ Wt_l,
    const float* __restrict__ bk2, const float* __restrict__ bq2,
    unsigned short* __restrict__ CSk_h, unsigned short* __restrict__ CSk_l,
    unsigned short* __restrict__ CSq_h, unsigned short* __restrict__ CSq_l)
{
    __shared__ __align__(16) unsigned short lds[16384];   // 32KB for <2,1>
    const int tid = threadIdx.x, lane = tid & 63;
    const int enc = blockIdx.x & 1, mT = blockIdx.x >> 1;
    const unsigned short* Ah_ = enc ? Hq_h : Hk_h;
    const unsigned short* Al_ = enc ? Hq_l : Hk_l;
    const float* b2 = enc ? bq2 : bk2;
    unsigned short* Ch = enc ? CSq_h : CSk_h;
    unsigned short* Cl = enc ? CSq_l : CSk_l;
    const int wm = (tid >> 8) & 1, wn = (tid >> 6) & 3;
    f32x4 acc[2][1];
#pragma unroll
    for (int i = 0; i < 2; ++i) acc[i][0] = (f32x4){0.f,0.f,0.f,0.f};
    lds_gemm<2,1>(lds, Ah_, Al_, 512, mT*64, Wt_h, Wt_l, 512, 2048 + enc*64, 0, 16, acc);
#pragma unroll
    for (int mi = 0; mi < 2; ++mi)
#pragma unroll
    for (int r = 0; r < 4; ++r) {
        const int row = mT*64 + wm*32 + mi*16 + (lane>>4)*4 + r;
        const int j = wn*16 + (lane&15);
        float p = acc[mi][0][r] + b2[j];
        p = tanhf(p) * PI_F;
        float s, c;
        sincosf(p, &s, &c);
        unsigned short h, l;
        split2(c, h, l);
        Ch[(size_t)row*128 + j] = h; Cl[(size_t)row*128 + j] = l;
        split2(s, h, l);
        Ch[(size_t)row*128 + 64 + j] = h; Cl[(size_t)row*128 + 64 + j] = l;
    }
}

// ---------------------------------------------------------------------------
// scores: 256 units (64 t-rows x 128 s-cols), lower-tri; upper zeroed.
// ---------------------------------------------------------------------------
__global__ __launch_bounds__(512) void scores_mfma(
    const unsigned short* __restrict__ CSq_h, const unsigned short* __restrict__ CSq_l,
    const unsigned short* __restrict__ CSk_h, const unsigned short* __restrict__ CSk_l,
    unsigned short* __restrict__ Ah, unsigned short* __restrict__ Al)
{
    const int u = blockIdx.x;
    const int b = u >> 7, tT = (u >> 3) & 15, sT = u & 7;
    if (sT * 128 > tT * 64 + 63) return;
    __shared__ __align__(16) unsigned short lds[24576];   // 48KB for <2,2>
    const int tid = threadIdx.x, lane = tid & 63;
    const int wm = (tid >> 8) & 1, wn = (tid >> 6) & 3;
    f32x4 acc[2][2];
#pragma unroll
    for (int i = 0; i < 2; ++i)
#pragma unroll
        for (int jj = 0; jj < 2; ++jj) acc[i][jj] = (f32x4){0.f,0.f,0.f,0.f};
    lds_gemm<2,2>(lds, CSq_h, CSq_l, 128, b*1024 + tT*64,
                  CSk_h, CSk_l, 128, b*1024 + sT*128, 0, 4, acc);
#pragma unroll
    for (int mi = 0; mi < 2; ++mi)
#pragma unroll
    for (int ni = 0; ni < 2; ++ni)
#pragma unroll
    for (int r = 0; r < 4; ++r) {
        const int t = tT*64 + wm*32 + mi*16 + (lane>>4)*4 + r;
        const int s = sT*128 + wn*32 + ni*16 + (lane&15);
        float v = (s <= t) ? acc[mi][ni][r] : 0.f;
        unsigned short h, l;
        split2(v, h, l);
        const size_t o = ((size_t)b*1024 + t) * 1024 + s;
        Ah[o] = h; Al[o] = l;
    }
}

// ---------------------------------------------------------------------------
// av: 512 units (s-chunks of 256 -> partials Rp[c]).
// ---------------------------------------------------------------------------
__global__ __launch_bounds__(512) void av_mfma(
    const unsigned short* __restrict__ Ah, const unsigned short* __restrict__ Al,
    const unsigned short* __restrict__ Vt_h, const unsigned short* __restrict__ Vt_l,
    float* __restrict__ Rp)
{
    const int u = blockIdx.x;
    const int c = u >> 7, b = (u >> 6) & 1, dT = (u >> 4) & 3, tT = u & 15;
    if (c * 256 > tT * 64 + 63) return;
    __shared__ __align__(16) unsigned short lds[24576];   // 48KB for <2,2>
    const int tid = threadIdx.x, lane = tid & 63;
    const int wm = (tid >> 8) & 1, wn = (tid >> 6) & 3;
    const int kLen = min(256, tT*64 + 64 - c*256);
    const int nk = kLen >> 5;
    f32x4 acc[2][2];
#pragma unroll
    for (int i = 0; i < 2; ++i)
#pragma unroll
        for (int jj = 0; jj < 2; ++jj) acc[i][jj] = (f32x4){0.f,0.f,0.f,0.f};
    lds_gemm<2,2>(lds, Ah, Al, 1024, b*1024 + tT*64,
                  Vt_h, Vt_l, 1024, b*512 + dT*128, c*256, nk, acc);
    float* Rb = Rp + (size_t)c * (M_ROWS * 512);
#pragma unroll
    for (int mi = 0; mi < 2; ++mi)
#pragma unroll
    for (int ni = 0; ni < 2; ++ni)
#pragma unroll
    for (int r = 0; r < 4; ++r) {
        const int row = b*1024 + tT*64 + wm*32 + mi*16 + (lane>>4)*4 + r;
        const int d = dT*128 + wn*32 + ni*16 + (lane&15);
        Rb[(size_t)row*512 + d] = acc[mi][ni][r];
    }
}

// ---------------------------------------------------------------------------
// out: 128 units of 128x64. LN fused: per-row stats via quad-shuffle, then
// A = LN(sum_c Rp) staged via transform; B = Wo^T. out = x + Y@Wo + bo.
// ---------------------------------------------------------------------------
__global__ __launch_bounds__(512) void out_mfma(
    const float* __restrict__ Rp,
    const float* __restrict__ lng, const float* __restrict__ lnb,
    const unsigned short* __restrict__ Wt_h, const unsigned short* __restrict__ Wt_l,
    const float* __restrict__ bo, const float* __restrict__ x,
    float* __restrict__ out)
{
    __shared__ __align__(16) unsigned short lds[24576];   // 48KB: 2x(4096+4096+2048+2048)
    constexpr int SZA = 4096, SZB = 2048, BUF = 12288;
    const int tid = threadIdx.x, lane = tid & 63;
    const int mT = blockIdx.x >> 3, nT = blockIdx.x & 7;
    const int mBase = mT * 128;
    const int wm = (tid >> 8) & 1, wn = (tid >> 6) & 3;

    // --- per-row LN stats (no barrier; quad = 4 lanes per row) ---
    const int rStat = tid >> 2;
    const int rowg = mBase + rStat;
    const int t = rowg & (L_SEQ - 1);
    const int nc = (t >> 8) + 1;
    const float scale = rsqrtf((float)(t + 1) * 64.0f);
    float s = 0.f, q = 0.f;
    {
        const float* p0 = Rp + (size_t)rowg * 512 + (tid & 3) * 128;
#pragma unroll 4
        for (int i = 0; i < 32; ++i) {
            float4 v = reinterpret_cast<const float4*>(p0)[i];
            for (int c = 1; c < nc; ++c) {
                float4 w = reinterpret_cast<const float4*>(p0 + (size_t)c * (M_ROWS*512))[i];
                v.x += w.x; v.y += w.y; v.z += w.z; v.w += w.w;
            }
            const float ux = v.x*scale, uy = v.y*scale, uz = v.z*scale, uw = v.w*scale;
            s += ux + uy + uz + uw;
            q += ux*ux + uy*uy + uz*uz + uw*uw;
        }
    }
    s += __shfl_xor(s, 1); q += __shfl_xor(q, 1);
    s += __shfl_xor(s, 2); q += __shfl_xor(q, 2);
    const float mu = s * (1.f / 512.f);
    const float ri = rsqrtf(q * (1.f / 512.f) - mu * mu + 1e-5f);

    // --- GEMM with transform-staged A ---
    f32x4 acc[4][1];
#pragma unroll
    for (int i = 0; i < 4; ++i) acc[i][0] = (f32x4){0.f,0.f,0.f,0.f};
    stage_y(Rp, rowg, nc, 0, scale, mu, ri, lng, lnb, lds, lds + SZA);
    stage_tile(Wt_h, 512, 1536 + nT*64, 0, lds + 2*SZA, 64);
    stage_tile(Wt_l, 512, 1536 + nT*64, 0, lds + 2*SZA + SZB, 64);
    for (int ks = 0; ks < 16; ++ks) {
        const int cur = (ks & 1) * BUF;
        const int nxt = cur ^ BUF;
        __syncthreads();
        if (ks + 1 < 16) {
            const int kk = (ks + 1) * 32;
            stage_y(Rp, rowg, nc, kk, scale, mu, ri, lng, lnb,
                    lds + nxt, lds + nxt + SZA);
            stage_tile(Wt_h, 512, 1536 + nT*64, kk, lds + nxt + 2*SZA, 64);
            stage_tile(Wt_l, 512, 1536 + nT*64, kk, lds + nxt + 2*SZA + SZB, 64);
        }
        const int lr = lane & 15, j = lane >> 4;
        bf16x8 ah[4], al[4], bh, bl;
#pragma unroll
        for (int mi = 0; mi < 4; ++mi) {
            const int r = wm*64 + mi*16 + lr;
            const int off = cur + r*32 + ((j ^ ((r>>1)&3)) << 3);
            ah[mi] = *(const bf16x8*)(lds + off);
            al[mi] = *(const bf16x8*)(lds + off + SZA);
        }
        {
            const int r = wn*16 + lr;
            const int off = cur + 2*SZA + r*32 + ((j ^ ((r>>1)&3)) << 3);
            bh = *(const bf16x8*)(lds + off);
            bl = *(const bf16x8*)(lds + off + SZB);
        }
#pragma unroll
        for (int mi = 0; mi < 4; ++mi) {
            acc[mi][0] = mfma16(ah[mi], bh, acc[mi][0]);
            acc[mi][0] = mfma16(ah[mi], bl, acc[mi][0]);
            acc[mi][0] = mfma16(al[mi], bh, acc[mi][0]);
        }
    }
#pragma unroll
    for (int mi = 0; mi < 4; ++mi)
#pragma unroll
    for (int r = 0; r < 4; ++r) {
        const int row = mBase + wm*64 + mi*16 + (lane>>4)*4 + r;
        const int col = nT*64 + wn*16 + (lane&15);
        out[(size_t)row*512 + col] =
            acc[mi][0][r] + bo[col] + x[(size_t)row*512 + col];
    }
}

// ---------------------------------------------------------------------------
extern "C" void kernel_launch(void* const* d_in, const int* in_sizes, int n_in,
                              void* d_out, int out_size, void* d_ws, size_t ws_size,
                              hipStream_t stream)
{
    const float* x   = (const float*)d_in[0];
    const float* Wk1 = (const float*)d_in[1];
    const float* bk1 = (const float*)d_in[2];
    const float* Wk2 = (const float*)d_in[3];
    const float* bk2 = (const float*)d_in[4];
    const float* Wq1 = (const float*)d_in[5];
    const float* bq1 = (const float*)d_in[6];
    const float* Wq2 = (const float*)d_in[7];
    const float* bq2 = (const float*)d_in[8];
    const float* Wv  = (const float*)d_in[9];
    const float* bv  = (const float*)d_in[10];
    const float* lng = (const float*)d_in[11];
    const float* lnb = (const float*)d_in[12];
    const float* Wo  = (const float*)d_in[13];
    const float* bo  = (const float*)d_in[14];
    float* out = (float*)d_out;

    unsigned short* us = (unsigned short*)d_ws;
    size_t o = 0;
    unsigned short* Wt_h  = us + o; o += (size_t)2176*512;
    unsigned short* Wt_l  = us + o; o += (size_t)2176*512;
    unsigned short* Hk_h  = us + o; o += (size_t)2048*512;
    unsigned short* Hk_l  = us + o; o += (size_t)2048*512;
    unsigned short* Hq_h  = us + o; o += (size_t)2048*512;
    unsigned short* Hq_l  = us + o; o += (size_t)2048*512;
    unsigned short* Vt_h  = us + o; o += (size_t)2*512*1024;
    unsigned short* Vt_l  = us + o; o += (size_t)2*512*1024;
    unsigned short* CSk_h = us + o; o += (size_t)2048*128;
    unsigned short* CSk_l = us + o; o += (size_t)2048*128;
    unsigned short* CSq_h = us + o; o += (size_t)2048*128;
    unsigned short* CSq_l = us + o; o += (size_t)2048*128;
    unsigned short* Ah    = us + o; o += (size_t)2*1024*1024;
    unsigned short* Al    = us + o; o += (size_t)2*1024*1024;
    float* Rp = (float*)(us + o);   o += (size_t)4 * 2048*512 * 2;

    prep<<<272, 512, 0, stream>>>(Wk1, Wq1, Wv, Wo, Wk2, Wq2, Wt_h, Wt_l);
    qkv_mfma<<<192, 512, 0, stream>>>(x, Wt_h, Wt_l, bk1, bq1, bv,
                                      Hk_h, Hk_l, Hq_h, Hq_l, Vt_h, Vt_l);
    phase_mfma<<<64, 512, 0, stream>>>(Hk_h, Hk_l, Hq_h, Hq_l, Wt_h, Wt_l,
                                       bk2, bq2, CSk_h, CSk_l, CSq_h, CSq_l);
    scores_mfma<<<256, 512, 0, stream>>>(CSq_h, CSq_l, CSk_h, CSk_l, Ah, Al);
    av_mfma<<<512, 512, 0, stream>>>(Ah, Al, Vt_h, Vt_l, Rp);
    out_mfma<<<128, 512, 0, stream>>>(Rp, lng, lnb, Wt_h, Wt_l, bo, x, out);
}

// Round 13
// 172.546 us; speedup vs baseline: 1.2738x; 1.2738x over previous
//
#include <hip/hip_runtime.h>
#include <math.h>

#define L_SEQ 1024
#define M_ROWS 2048
#define PI_F 3.14159265358979323846f

typedef short bf16x8 __attribute__((ext_vector_type(8)));
typedef float f32x4 __attribute__((ext_vector_type(4)));

__device__ __forceinline__ unsigned short bf16_rne(float x) {
    union { float f; unsigned u; } v; v.f = x;
    unsigned r = v.u + 0x7fffu + ((v.u >> 16) & 1u);
    return (unsigned short)(r >> 16);
}
__device__ __forceinline__ float bf16_tof(unsigned short h) {
    union { unsigned u; float f; } v; v.u = ((unsigned)h) << 16;
    return v.f;
}
__device__ __forceinline__ void split2(float x, unsigned short &h, unsigned short &l) {
    h = bf16_rne(x);
    l = bf16_rne(x - bf16_tof(h));
}
__device__ __forceinline__ float gelu_exact(float x) {
    return 0.5f * x * (1.0f + erff(x * 0.70710678118654752f));
}
__device__ __forceinline__ f32x4 mfma16(bf16x8 a, bf16x8 b, f32x4 c) {
    return __builtin_amdgcn_mfma_f32_16x16x32_bf16(a, b, c, 0, 0, 0);
}
__device__ __forceinline__ void gload_lds16(const unsigned short* g, unsigned short* l) {
    __builtin_amdgcn_global_load_lds(
        (const __attribute__((address_space(1))) void*)g,
        (__attribute__((address_space(3))) void*)l, 16, 0, 0);
}

// Stage R x 32 bf16 tile into LDS (row = 64B), pre-swizzled source.
__device__ __forceinline__ void stage_tile(
    const unsigned short* __restrict__ src, int ld, int rowBase, int k0,
    unsigned short* lds_tile, int R)
{
    const int tid = threadIdx.x;
    if (tid < R * 4) {
        const int r = tid >> 2;
        const int c = (tid & 3) ^ ((r >> 1) & 3);
        const unsigned short* g = src + (size_t)(rowBase + r) * ld + k0 + c * 8;
        unsigned short* l = lds_tile + (tid >> 6) * 512;   // wave-uniform base
        gload_lds16(g, l);
    }
}

// Stage 128 rows x 32 k from f32 source: load, split hi/lo, ds_write_b128
// into the same swizzled layout stage_tile produces. 512 threads exactly.
__device__ __forceinline__ void stage_xf32(
    const float* __restrict__ src, int ld, int rowBase, int k0,
    unsigned short* dh, unsigned short* dl)
{
    const int tid = threadIdx.x;
    const int r = tid >> 2, slot = tid & 3;
    const float* p = src + (size_t)(rowBase + r) * ld + k0 + slot * 8;
    float4 a = *reinterpret_cast<const float4*>(p);
    float4 b = *reinterpret_cast<const float4*>(p + 4);
    bf16x8 h, l;
    unsigned short th, tl;
    split2(a.x, th, tl); h[0] = (short)th; l[0] = (short)tl;
    split2(a.y, th, tl); h[1] = (short)th; l[1] = (short)tl;
    split2(a.z, th, tl); h[2] = (short)th; l[2] = (short)tl;
    split2(a.w, th, tl); h[3] = (short)th; l[3] = (short)tl;
    split2(b.x, th, tl); h[4] = (short)th; l[4] = (short)tl;
    split2(b.y, th, tl); h[5] = (short)th; l[5] = (short)tl;
    split2(b.z, th, tl); h[6] = (short)th; l[6] = (short)tl;
    split2(b.w, th, tl); h[7] = (short)th; l[7] = (short)tl;
    const int addr = r * 32 + ((slot ^ ((r >> 1) & 3)) << 3);
    *reinterpret_cast<bf16x8*>(dh + addr) = h;
    *reinterpret_cast<bf16x8*>(dl + addr) = l;
}

// LDS-staged split-bf16 GEMM core (both operands pre-split bf16 in global).
// 512 threads = 8 waves (2m x 4n). Block tile = (32*MI) x (64*NI).
template<int MI, int NI>
__device__ __forceinline__ void lds_gemm(
    unsigned short* lds,
    const unsigned short* Ah_, const unsigned short* Al_, int lda, int aRow,
    const unsigned short* Bh_, const unsigned short* Bl_, int ldb, int bRow,
    int k0, int nk, f32x4 (&acc)[MI][NI])
{
    constexpr int RA = MI * 32, RB = NI * 64;
    constexpr int SZA = RA * 32;
    constexpr int SZB = RB * 32;
    constexpr int BUF = 2 * SZA + 2 * SZB;
    const int tid = threadIdx.x, lane = tid & 63;
    const int wm = (tid >> 8) & 1;
    const int wn = (tid >> 6) & 3;

    stage_tile(Ah_, lda, aRow, k0, lds,                 RA);
    stage_tile(Al_, lda, aRow, k0, lds + SZA,           RA);
    stage_tile(Bh_, ldb, bRow, k0, lds + 2 * SZA,       RB);
    stage_tile(Bl_, ldb, bRow, k0, lds + 2 * SZA + SZB, RB);

    for (int ks = 0; ks < nk; ++ks) {
        const int cur = (ks & 1) * BUF;
        const int nxt = ((ks & 1) ^ 1) * BUF;
        __syncthreads();
        if (ks + 1 < nk) {
            const int kk = k0 + (ks + 1) * 32;
            stage_tile(Ah_, lda, aRow, kk, lds + nxt,                 RA);
            stage_tile(Al_, lda, aRow, kk, lds + nxt + SZA,           RA);
            stage_tile(Bh_, ldb, bRow, kk, lds + nxt + 2 * SZA,       RB);
            stage_tile(Bl_, ldb, bRow, kk, lds + nxt + 2 * SZA + SZB, RB);
        }
        const int lr = lane & 15, j = lane >> 4;
        bf16x8 ah[MI], al[MI], bh[NI], bl[NI];
#pragma unroll
        for (int mi = 0; mi < MI; ++mi) {
            const int r = wm * (MI * 16) + mi * 16 + lr;
            const int off = cur + r * 32 + ((j ^ ((r >> 1) & 3)) << 3);
            ah[mi] = *(const bf16x8*)(lds + off);
            al[mi] = *(const bf16x8*)(lds + off + SZA);
        }
#pragma unroll
        for (int ni = 0; ni < NI; ++ni) {
            const int r = wn * (NI * 16) + ni * 16 + lr;
            const int off = cur + 2 * SZA + r * 32 + ((j ^ ((r >> 1) & 3)) << 3);
            bh[ni] = *(const bf16x8*)(lds + off);
            bl[ni] = *(const bf16x8*)(lds + off + SZB);
        }
#pragma unroll
        for (int mi = 0; mi < MI; ++mi)
#pragma unroll
            for (int ni = 0; ni < NI; ++ni) {
                acc[mi][ni] = mfma16(ah[mi], bh[ni], acc[mi][ni]);
                acc[mi][ni] = mfma16(ah[mi], bl[ni], acc[mi][ni]);
                acc[mi][ni] = mfma16(al[mi], bh[ni], acc[mi][ni]);
            }
    }
}

// ---------------------------------------------------------------------------
// prep: weights only — transpose + hi/lo split into Wt[row=n][k].
// rows: [0,512)=Wk1^T, [512,1024)=Wq1^T, [1024,1536)=Wv^T,
//       [1536,2048)=Wo^T, [2048,2112)=Wk2^T, [2112,2176)=Wq2^T
// ---------------------------------------------------------------------------
__global__ __launch_bounds__(512) void prep(
    const float* __restrict__ Wk1, const float* __restrict__ Wq1,
    const float* __restrict__ Wv,  const float* __restrict__ Wo,
    const float* __restrict__ Wk2, const float* __restrict__ Wq2,
    unsigned short* __restrict__ Wt_h, unsigned short* __restrict__ Wt_l)
{
    const int u = blockIdx.x;
    const int tid = threadIdx.x;
    __shared__ float T[64 * 65];
    const int kT = u & 7, ty = u >> 3;
    const float* src; int srcN, dstRowBase, nBase;
    if (ty < 8)       { src = Wk1; srcN = 512; dstRowBase = 0;    nBase = ty * 64; }
    else if (ty < 16) { src = Wq1; srcN = 512; dstRowBase = 512;  nBase = (ty-8)*64; }
    else if (ty < 24) { src = Wv;  srcN = 512; dstRowBase = 1024; nBase = (ty-16)*64; }
    else if (ty < 32) { src = Wo;  srcN = 512; dstRowBase = 1536; nBase = (ty-24)*64; }
    else if (ty == 32){ src = Wk2; srcN = 64;  dstRowBase = 2048; nBase = 0; }
    else              { src = Wq2; srcN = 64;  dstRowBase = 2112; nBase = 0; }
    const int k0 = kT * 64;
    {
        const int r = tid >> 3, c0 = (tid & 7) * 8;
#pragma unroll
        for (int i = 0; i < 2; ++i) {
            float4 v = *reinterpret_cast<const float4*>(
                src + (size_t)(k0 + r) * srcN + nBase + c0 + i*4);
            T[r*65 + c0+i*4+0] = v.x; T[r*65 + c0+i*4+1] = v.y;
            T[r*65 + c0+i*4+2] = v.z; T[r*65 + c0+i*4+3] = v.w;
        }
    }
    __syncthreads();
    {
        const int n = tid >> 3, kk0 = (tid & 7) * 8;
        const size_t base = (size_t)(dstRowBase + nBase + n) * 512 + k0 + kk0;
#pragma unroll
        for (int i = 0; i < 8; ++i) {
            unsigned short h, l;
            split2(T[(kk0 + i)*65 + n], h, l);
            Wt_h[base + i] = h; Wt_l[base + i] = l;
        }
    }
}

// ---------------------------------------------------------------------------
// qkv: 192 units of 128x128. A staged from f32 x (split on the fly);
// B = Wt via global_load_lds. gelu on k/q segs, V transposed per batch.
// ---------------------------------------------------------------------------
__global__ __launch_bounds__(512) void qkv_mfma(
    const float* __restrict__ x,
    const unsigned short* __restrict__ Wt_h, const unsigned short* __restrict__ Wt_l,
    const float* __restrict__ bk1, const float* __restrict__ bq1, const float* __restrict__ bv,
    unsigned short* __restrict__ Hk_h, unsigned short* __restrict__ Hk_l,
    unsigned short* __restrict__ Hq_h, unsigned short* __restrict__ Hq_l,
    unsigned short* __restrict__ Vt_h, unsigned short* __restrict__ Vt_l)
{
    __shared__ __align__(16) unsigned short lds[32768];   // 64KB
    constexpr int SZA = 4096, SZB = 4096, BUF = 16384;
    const int tid = threadIdx.x, lane = tid & 63;
    const int nT = blockIdx.x % 12, mT = blockIdx.x / 12;
    const int mBase = mT * 128, nBase = nT * 128;
    const int wm = (tid >> 8) & 1, wn = (tid >> 6) & 3;
    f32x4 acc[4][2];
#pragma unroll
    for (int i = 0; i < 4; ++i)
#pragma unroll
        for (int jj = 0; jj < 2; ++jj) acc[i][jj] = (f32x4){0.f,0.f,0.f,0.f};

    stage_xf32(x, 512, mBase, 0, lds, lds + SZA);
    stage_tile(Wt_h, 512, nBase, 0, lds + 2*SZA, 128);
    stage_tile(Wt_l, 512, nBase, 0, lds + 2*SZA + SZB, 128);
    for (int ks = 0; ks < 16; ++ks) {
        const int cur = (ks & 1) * BUF;
        const int nxt = cur ^ BUF;
        __syncthreads();
        if (ks + 1 < 16) {
            const int kk = (ks + 1) * 32;
            stage_xf32(x, 512, mBase, kk, lds + nxt, lds + nxt + SZA);
            stage_tile(Wt_h, 512, nBase, kk, lds + nxt + 2*SZA, 128);
            stage_tile(Wt_l, 512, nBase, kk, lds + nxt + 2*SZA + SZB, 128);
        }
        const int lr = lane & 15, j = lane >> 4;
        bf16x8 ah[4], al[4], bh[2], bl[2];
#pragma unroll
        for (int mi = 0; mi < 4; ++mi) {
            const int r = wm*64 + mi*16 + lr;
            const int off = cur + r*32 + ((j ^ ((r>>1)&3)) << 3);
            ah[mi] = *(const bf16x8*)(lds + off);
            al[mi] = *(const bf16x8*)(lds + off + SZA);
        }
#pragma unroll
        for (int ni = 0; ni < 2; ++ni) {
            const int r = wn*32 + ni*16 + lr;
            const int off = cur + 2*SZA + r*32 + ((j ^ ((r>>1)&3)) << 3);
            bh[ni] = *(const bf16x8*)(lds + off);
            bl[ni] = *(const bf16x8*)(lds + off + SZB);
        }
#pragma unroll
        for (int mi = 0; mi < 4; ++mi)
#pragma unroll
            for (int ni = 0; ni < 2; ++ni) {
                acc[mi][ni] = mfma16(ah[mi], bh[ni], acc[mi][ni]);
                acc[mi][ni] = mfma16(ah[mi], bl[ni], acc[mi][ni]);
                acc[mi][ni] = mfma16(al[mi], bh[ni], acc[mi][ni]);
            }
    }
    const int seg = nBase >> 9;
    const float* bias = (seg == 0) ? bk1 : (seg == 1) ? bq1 : bv;
#pragma unroll
    for (int mi = 0; mi < 4; ++mi)
#pragma unroll
    for (int ni = 0; ni < 2; ++ni)
#pragma unroll
    for (int r = 0; r < 4; ++r) {
        const int row = mBase + wm*64 + mi*16 + (lane>>4)*4 + r;
        const int col = nBase + wn*32 + ni*16 + (lane&15);
        const int nW = col & 511;
        float v = acc[mi][ni][r] + bias[nW];
        if (seg < 2) v = gelu_exact(v);
        unsigned short h, l;
        split2(v, h, l);
        if (seg == 0)      { Hk_h[(size_t)row*512 + nW] = h; Hk_l[(size_t)row*512 + nW] = l; }
        else if (seg == 1) { Hq_h[(size_t)row*512 + nW] = h; Hq_l[(size_t)row*512 + nW] = l; }
        else {
            const size_t o = (size_t)((row >> 10)*512 + nW) * 1024 + (row & 1023);
            Vt_h[o] = h; Vt_l[o] = l;
        }
    }
}

// ---------------------------------------------------------------------------
// phase heads: 64 units of 64 rows; p = tanh(H@W2+b2)*pi -> [cos|sin] hi/lo.
// ---------------------------------------------------------------------------
__global__ __launch_bounds__(512) void phase_mfma(
    const unsigned short* __restrict__ Hk_h, const unsigned short* __restrict__ Hk_l,
    const unsigned short* __restrict__ Hq_h, const unsigned short* __restrict__ Hq_l,
    const unsigned short* __restrict__ Wt_h, const unsigned short* __restrict__ Wt_l,
    const float* __restrict__ bk2, const float* __restrict__ bq2,
    unsigned short* __restrict__ CSk_h, unsigned short* __restrict__ CSk_l,
    unsigned short* __restrict__ CSq_h, unsigned short* __restrict__ CSq_l)
{
    __shared__ __align__(16) unsigned short lds[16384];   // 32KB for <2,1>
    const int tid = threadIdx.x, lane = tid & 63;
    const int enc = blockIdx.x & 1, mT = blockIdx.x >> 1;
    const unsigned short* Ah_ = enc ? Hq_h : Hk_h;
    const unsigned short* Al_ = enc ? Hq_l : Hk_l;
    const float* b2 = enc ? bq2 : bk2;
    unsigned short* Ch = enc ? CSq_h : CSk_h;
    unsigned short* Cl = enc ? CSq_l : CSk_l;
    const int wm = (tid >> 8) & 1, wn = (tid >> 6) & 3;
    f32x4 acc[2][1];
#pragma unroll
    for (int i = 0; i < 2; ++i) acc[i][0] = (f32x4){0.f,0.f,0.f,0.f};
    lds_gemm<2,1>(lds, Ah_, Al_, 512, mT*64, Wt_h, Wt_l, 512, 2048 + enc*64, 0, 16, acc);
#pragma unroll
    for (int mi = 0; mi < 2; ++mi)
#pragma unroll
    for (int r = 0; r < 4; ++r) {
        const int row = mT*64 + wm*32 + mi*16 + (lane>>4)*4 + r;
        const int j = wn*16 + (lane&15);
        float p = acc[mi][0][r] + b2[j];
        p = tanhf(p) * PI_F;
        float s, c;
        sincosf(p, &s, &c);
        unsigned short h, l;
        split2(c, h, l);
        Ch[(size_t)row*128 + j] = h; Cl[(size_t)row*128 + j] = l;
        split2(s, h, l);
        Ch[(size_t)row*128 + 64 + j] = h; Cl[(size_t)row*128 + 64 + j] = l;
    }
}

// ---------------------------------------------------------------------------
// scores: 256 units (64 t-rows x 128 s-cols), lower-tri; upper zeroed.
// ---------------------------------------------------------------------------
__global__ __launch_bounds__(512) void scores_mfma(
    const unsigned short* __restrict__ CSq_h, const unsigned short* __restrict__ CSq_l,
    const unsigned short* __restrict__ CSk_h, const unsigned short* __restrict__ CSk_l,
    unsigned short* __restrict__ Ah, unsigned short* __restrict__ Al)
{
    const int u = blockIdx.x;
    const int b = u >> 7, tT = (u >> 3) & 15, sT = u & 7;
    if (sT * 128 > tT * 64 + 63) return;
    __shared__ __align__(16) unsigned short lds[24576];   // 48KB for <2,2>
    const int tid = threadIdx.x, lane = tid & 63;
    const int wm = (tid >> 8) & 1, wn = (tid >> 6) & 3;
    f32x4 acc[2][2];
#pragma unroll
    for (int i = 0; i < 2; ++i)
#pragma unroll
        for (int jj = 0; jj < 2; ++jj) acc[i][jj] = (f32x4){0.f,0.f,0.f,0.f};
    lds_gemm<2,2>(lds, CSq_h, CSq_l, 128, b*1024 + tT*64,
                  CSk_h, CSk_l, 128, b*1024 + sT*128, 0, 4, acc);
#pragma unroll
    for (int mi = 0; mi < 2; ++mi)
#pragma unroll
    for (int ni = 0; ni < 2; ++ni)
#pragma unroll
    for (int r = 0; r < 4; ++r) {
        const int t = tT*64 + wm*32 + mi*16 + (lane>>4)*4 + r;
        const int s = sT*128 + wn*32 + ni*16 + (lane&15);
        float v = (s <= t) ? acc[mi][ni][r] : 0.f;
        unsigned short h, l;
        split2(v, h, l);
        const size_t o = ((size_t)b*1024 + t) * 1024 + s;
        Ah[o] = h; Al[o] = l;
    }
}

// ---------------------------------------------------------------------------
// av: 512 units (s-chunks of 256 -> partials Rp[c]).
// ---------------------------------------------------------------------------
__global__ __launch_bounds__(512) void av_mfma(
    const unsigned short* __restrict__ Ah, const unsigned short* __restrict__ Al,
    const unsigned short* __restrict__ Vt_h, const unsigned short* __restrict__ Vt_l,
    float* __restrict__ Rp)
{
    const int u = blockIdx.x;
    const int c = u >> 7, b = (u >> 6) & 1, dT = (u >> 4) & 3, tT = u & 15;
    if (c * 256 > tT * 64 + 63) return;
    __shared__ __align__(16) unsigned short lds[24576];   // 48KB for <2,2>
    const int tid = threadIdx.x, lane = tid & 63;
    const int wm = (tid >> 8) & 1, wn = (tid >> 6) & 3;
    const int kLen = min(256, tT*64 + 64 - c*256);
    const int nk = kLen >> 5;
    f32x4 acc[2][2];
#pragma unroll
    for (int i = 0; i < 2; ++i)
#pragma unroll
        for (int jj = 0; jj < 2; ++jj) acc[i][jj] = (f32x4){0.f,0.f,0.f,0.f};
    lds_gemm<2,2>(lds, Ah, Al, 1024, b*1024 + tT*64,
                  Vt_h, Vt_l, 1024, b*512 + dT*128, c*256, nk, acc);
    float* Rb = Rp + (size_t)c * (M_ROWS * 512);
#pragma unroll
    for (int mi = 0; mi < 2; ++mi)
#pragma unroll
    for (int ni = 0; ni < 2; ++ni)
#pragma unroll
    for (int r = 0; r < 4; ++r) {
        const int row = b*1024 + tT*64 + wm*32 + mi*16 + (lane>>4)*4 + r;
        const int d = dT*128 + wn*32 + ni*16 + (lane&15);
        Rb[(size_t)row*512 + d] = acc[mi][ni][r];
    }
}

// ---------------------------------------------------------------------------
// ln: 256 blocks x 8 rows; LN((sum_c Rp)/sqrt((t+1)K))*g + b -> Y hi/lo.
// ---------------------------------------------------------------------------
__global__ __launch_bounds__(512) void ln_kernel(
    const float* __restrict__ Rp, const float* __restrict__ g,
    const float* __restrict__ bb,
    unsigned short* __restrict__ Yh, unsigned short* __restrict__ Yl)
{
    __shared__ float fbuf[16];
    const int tid = threadIdx.x;
    const int lane = tid & 63, wid = tid >> 6;
    for (int i = 0; i < 8; ++i) {
        const int row = blockIdx.x * 8 + i;
        const int t = row & (L_SEQ - 1);
        const int nc = (t >> 8) + 1;
        const float scale = rsqrtf((float)(t + 1) * 64.0f);
        float v = 0.f;
        for (int c = 0; c < nc; ++c)
            v += Rp[(size_t)c * (M_ROWS * 512) + (size_t)row * 512 + tid];
        v *= scale;
        float s = v, q = v * v;
#pragma unroll
        for (int off = 32; off >= 1; off >>= 1) {
            s += __shfl_down(s, off);
            q += __shfl_down(q, off);
        }
        if (lane == 0) { fbuf[wid] = s; fbuf[8 + wid] = q; }
        __syncthreads();
        float S = 0.f, Q = 0.f;
#pragma unroll
        for (int w = 0; w < 8; ++w) { S += fbuf[w]; Q += fbuf[8 + w]; }
        const float mu  = S * (1.f / 512.f);
        const float var = Q * (1.f / 512.f) - mu * mu;
        const float rr = rsqrtf(var + 1e-5f);
        const float y = (v - mu) * rr * g[tid] + bb[tid];
        unsigned short h, l;
        split2(y, h, l);
        Yh[(size_t)row*512 + tid] = h;
        Yl[(size_t)row*512 + tid] = l;
        __syncthreads();
    }
}

// ---------------------------------------------------------------------------
// out: 128 units of 128x64; out = x + Y @ Wo + bo.
// ---------------------------------------------------------------------------
__global__ __launch_bounds__(512) void out_mfma(
    const unsigned short* __restrict__ Yh, const unsigned short* __restrict__ Yl,
    const unsigned short* __restrict__ Wt_h, const unsigned short* __restrict__ Wt_l,
    const float* __restrict__ bo, const float* __restrict__ x,
    float* __restrict__ out)
{
    __shared__ __align__(16) unsigned short lds[24576];   // 48KB for <4,1>
    const int tid = threadIdx.x, lane = tid & 63;
    const int mT = blockIdx.x >> 3, nT = blockIdx.x & 7;
    const int mBase = mT * 128;
    const int wm = (tid >> 8) & 1, wn = (tid >> 6) & 3;
    f32x4 acc[4][1];
#pragma unroll
    for (int i = 0; i < 4; ++i) acc[i][0] = (f32x4){0.f,0.f,0.f,0.f};
    lds_gemm<4,1>(lds, Yh, Yl, 512, mBase, Wt_h, Wt_l, 512, 1536 + nT*64, 0, 16, acc);
#pragma unroll
    for (int mi = 0; mi < 4; ++mi)
#pragma unroll
    for (int r = 0; r < 4; ++r) {
        const int row = mBase + wm*64 + mi*16 + (lane>>4)*4 + r;
        const int col = nT*64 + wn*16 + (lane&15);
        out[(size_t)row*512 + col] =
            acc[mi][0][r] + bo[col] + x[(size_t)row*512 + col];
    }
}

// ---------------------------------------------------------------------------
extern "C" void kernel_launch(void* const* d_in, const int* in_sizes, int n_in,
                              void* d_out, int out_size, void* d_ws, size_t ws_size,
                              hipStream_t stream)
{
    const float* x   = (const float*)d_in[0];
    const float* Wk1 = (const float*)d_in[1];
    const float* bk1 = (const float*)d_in[2];
    const float* Wk2 = (const float*)d_in[3];
    const float* bk2 = (const float*)d_in[4];
    const float* Wq1 = (const float*)d_in[5];
    const float* bq1 = (const float*)d_in[6];
    const float* Wq2 = (const float*)d_in[7];
    const float* bq2 = (const float*)d_in[8];
    const float* Wv  = (const float*)d_in[9];
    const float* bv  = (const float*)d_in[10];
    const float* lng = (const float*)d_in[11];
    const float* lnb = (const float*)d_in[12];
    const float* Wo  = (const float*)d_in[13];
    const float* bo  = (const float*)d_in[14];
    float* out = (float*)d_out;

    unsigned short* us = (unsigned short*)d_ws;
    size_t o = 0;
    unsigned short* Wt_h  = us + o; o += (size_t)2176*512;
    unsigned short* Wt_l  = us + o; o += (size_t)2176*512;
    unsigned short* Yh    = us + o; o += (size_t)2048*512;
    unsigned short* Yl    = us + o; o += (size_t)2048*512;
    unsigned short* Hk_h  = us + o; o += (size_t)2048*512;
    unsigned short* Hk_l  = us + o; o += (size_t)2048*512;
    unsigned short* Hq_h  = us + o; o += (size_t)2048*512;
    unsigned short* Hq_l  = us + o; o += (size_t)2048*512;
    unsigned short* Vt_h  = us + o; o += (size_t)2*512*1024;
    unsigned short* Vt_l  = us + o; o += (size_t)2*512*1024;
    unsigned short* CSk_h = us + o; o += (size_t)2048*128;
    unsigned short* CSk_l = us + o; o += (size_t)2048*128;
    unsigned short* CSq_h = us + o; o += (size_t)2048*128;
    unsigned short* CSq_l = us + o; o += (size_t)2048*128;
    unsigned short* Ah    = us + o; o += (size_t)2*1024*1024;
    unsigned short* Al    = us + o; o += (size_t)2*1024*1024;
    float* Rp = (float*)(us + o);   o += (size_t)4 * 2048*512 * 2;

    prep<<<272, 512, 0, stream>>>(Wk1, Wq1, Wv, Wo, Wk2, Wq2, Wt_h, Wt_l);
    qkv_mfma<<<192, 512, 0, stream>>>(x, Wt_h, Wt_l, bk1, bq1, bv,
                                      Hk_h, Hk_l, Hq_h, Hq_l, Vt_h, Vt_l);
    phase_mfma<<<64, 512, 0, stream>>>(Hk_h, Hk_l, Hq_h, Hq_l, Wt_h, Wt_l,
                                       bk2, bq2, CSk_h, CSk_l, CSq_h, CSq_l);
    scores_mfma<<<256, 512, 0, stream>>>(CSq_h, CSq_l, CSk_h, CSk_l, Ah, Al);
    av_mfma<<<512, 512, 0, stream>>>(Ah, Al, Vt_h, Vt_l, Rp);
    ln_kernel<<<256, 512, 0, stream>>>(Rp, lng, lnb, Yh, Yl);
    out_mfma<<<128, 512, 0, stream>>>(Yh, Yl, Wt_h, Wt_l, bo, x, out);
}